// Round 8
// baseline (303.830 us; speedup 1.0000x reference)
//
#include <hip/hip_runtime.h>

// SpatialAttention: B=32, C=512, D=64, N=1024 (H=W=32)
#define BB 32
#define CC 512
#define DD 64
#define NN 1024
#define GRP 16                // batches per P-buffer group
#define NGRP (BB / GRP)       // 2 groups

typedef float4 f4;
typedef __attribute__((ext_vector_type(8))) short bf16x8;     // 8 bf16 = 4 VGPRs (MFMA A/B frag)
typedef __attribute__((ext_vector_type(4))) float f32x4;      // MFMA C/D frag
typedef __attribute__((ext_vector_type(4))) unsigned short us4;
typedef __attribute__((ext_vector_type(8))) unsigned short us8;

__device__ inline unsigned short bf16rn(float f) {
  union { float f; unsigned u; } v; v.f = f;
  unsigned r = v.u + 0x7fff + ((v.u >> 16) & 1);   // round-to-nearest-even
  return (unsigned short)(r >> 16);
}

__device__ inline void gl_lds16(const void* g, void* l) {
  // async global->LDS, 16B/lane; LDS dest = wave-uniform base + lane*16
  __builtin_amdgcn_global_load_lds(
      (const __attribute__((address_space(1))) unsigned int*)g,
      (__attribute__((address_space(3))) unsigned int*)l, 16, 0, 0);
}

__device__ inline void wait_vm0_barrier() {
  asm volatile("s_waitcnt vmcnt(0)" ::: "memory");
  __builtin_amdgcn_s_barrier();
}

// T1: chunked XCD swizzle. nwg%8==0 required.
__device__ inline int xcd_swz(int bid, int nwg) {
  return (bid & 7) * (nwg >> 3) + (bid >> 3);
}

// ---- BK=32 GEMM core: C[128x128] += A[M][K]*Bt[N][K]^T ----
// 3 LDS buffers (48 KB total -> 3 blocks/CU), prefetch distance 2, COUNTED vmcnt:
//   iter i: vmcnt(4)   // tile i's 4 loads retired; tile i+1's 4 stay in flight
//           s_barrier
//           stage(i+2) // writes buffer last read in iter i-1 (all waves pre-barrier) - safe
//           8 ds_read_b128 + 16 MFMA on tile i
// Tile i+2's loads are waited 2 FULL iterations after issue -> latency covered.
// Swizzle (BK=32: 4 16B-slots/row): slot s of row r holds k-group (s ^ ((r>>1)&3)).
// Bank check: lane(fm,kq) reads row wm+i*16+fm, slot kq^((fm>>1)&3) -> 8 lanes per
// 4-bank group, uniform over 32 banks = conflict-free (2-way aliasing is free).
template <int KDIM>
__device__ inline void gemm_core32(const unsigned short* __restrict__ A,
                                   const unsigned short* __restrict__ Bt,
                                   int m0, int n0, int tid,
                                   unsigned short* sA, unsigned short* sB,  // 3 x 4096 shorts each
                                   f32x4 acc[4][4]) {
  constexpr int NT = KDIM / 32;
  const int wave = tid >> 6, lane = tid & 63;
  const int wm = (wave & 1) * 64, wn = (wave >> 1) * 64;
  const int fm = lane & 15;             // fragment row (m or n)
  const int kq = lane >> 4;             // fragment k-group (0..3)
  const int srow = lane >> 2;           // staging: row within 16-row chunk (0..15)
  const int sg8  = ((lane & 3) ^ ((lane >> 3) & 3)) * 8;   // staging src k-offset (swizzled)
  const int slotA = (kq ^ ((fm >> 1) & 3)) * 8;            // ds_read slot offset

  const unsigned short* ga = A  + (size_t)(m0 + srow) * KDIM + sg8;
  const unsigned short* gb = Bt + (size_t)(n0 + srow) * KDIM + sg8;

  auto stage = [&](int buf, int k0) {   // 4 gl_lds16 per wave (2 A + 2 B)
#pragma unroll
    for (int t = 0; t < 2; ++t) {
      const int R0 = wave * 32 + t * 16;    // 16-row chunk base
      gl_lds16(ga + (size_t)R0 * KDIM + k0, sA + buf * 4096 + R0 * 32);
      gl_lds16(gb + (size_t)R0 * KDIM + k0, sB + buf * 4096 + R0 * 32);
    }
  };

  stage(0, 0);
  stage(1, 32);

  int cur = 0;
  for (int i = 0; i < NT; ++i) {
    if (i + 1 < NT) {
      asm volatile("s_waitcnt vmcnt(4)" ::: "memory");   // tile i done; i+1 in flight
    } else {
      asm volatile("s_waitcnt vmcnt(0)" ::: "memory");   // last tile
    }
    __builtin_amdgcn_s_barrier();
    if (i + 2 < NT) {
      int nb = cur + 2; if (nb >= 3) nb -= 3;
      stage(nb, (i + 2) * 32);
    }
    const unsigned short* pA = sA + cur * 4096;
    const unsigned short* pB = sB + cur * 4096;
    bf16x8 af[4], bfr[4];
#pragma unroll
    for (int ii = 0; ii < 4; ++ii) {
      af[ii]  = *(const bf16x8*)(pA + (wm + ii * 16 + fm) * 32 + slotA);
      bfr[ii] = *(const bf16x8*)(pB + (wn + ii * 16 + fm) * 32 + slotA);
    }
#pragma unroll
    for (int ii = 0; ii < 4; ++ii)
#pragma unroll
      for (int j = 0; j < 4; ++j)
        acc[ii][j] = __builtin_amdgcn_mfma_f32_16x16x32_bf16(af[ii], bfr[j], acc[ii][j], 0, 0, 0);
    cur += 1; if (cur >= 3) cur -= 3;
  }
}

// ---------------- prep: weights -> bf16 ----------------
__global__ __launch_bounds__(256) void prep_w(
    const float* __restrict__ qw, const float* __restrict__ kw, const float* __restrict__ vw,
    const float* __restrict__ qb, const float* __restrict__ kb, const float* __restrict__ vb,
    const float* __restrict__ ow,
    unsigned short* __restrict__ wcat, unsigned short* __restrict__ owb,
    float* __restrict__ bcat) {
  int idx = blockIdx.x * 256 + threadIdx.x;
  if (idx < 640 * 512) {
    int row = idx >> 9;
    float v = (row < 64) ? qw[idx] : (row < 128) ? kw[idx - 64 * 512] : vw[idx - 128 * 512];
    wcat[idx] = bf16rn(v);
    if (idx < 640) bcat[idx] = (idx < 64) ? qb[idx] : (idx < 128) ? kb[idx - 64] : vb[idx - 128];
  } else {
    int j = idx - 640 * 512;
    owb[j] = bf16rn(ow[j]);
  }
}

// ---------------- prep: A[b][i][c] = bf16(x[b][c][i] + pos[c][i]) ----------------
__global__ __launch_bounds__(256) void prep_x(const float* __restrict__ x,
                                              const float* __restrict__ pos,
                                              unsigned short* __restrict__ A) {
  __shared__ float t[64][65];
  const int b = blockIdx.z, i0 = blockIdx.x * 64, c0 = blockIdx.y * 64;
  const int tid = threadIdx.x;
  const int ci = tid >> 4, il = (tid & 15) * 4;
  const float* xb = x + (size_t)b * CC * NN;
#pragma unroll
  for (int r = 0; r < 4; ++r) {
    int cl = r * 16 + ci;
    f4 xv = *(const f4*)(xb  + (size_t)(c0 + cl) * NN + i0 + il);
    f4 pv = *(const f4*)(pos + (size_t)(c0 + cl) * NN + i0 + il);
    t[cl][il + 0] = xv.x + pv.x;
    t[cl][il + 1] = xv.y + pv.y;
    t[cl][il + 2] = xv.z + pv.z;
    t[cl][il + 3] = xv.w + pv.w;
  }
  __syncthreads();
  const int iw = tid >> 2, cw = (tid & 3) * 16;
  unsigned short* dst = A + ((size_t)b * NN + i0 + iw) * CC + c0 + cw;
  us8 p0, p1;
#pragma unroll
  for (int j = 0; j < 8; ++j) p0[j] = bf16rn(t[cw + j][iw]);
#pragma unroll
  for (int j = 0; j < 8; ++j) p1[j] = bf16rn(t[cw + 8 + j][iw]);
  *(us8*)dst = p0;
  *(us8*)(dst + 8) = p1;
}

// ---------------- QKV projection GEMM ----------------
__global__ __launch_bounds__(256) void proj_gemm(
    const unsigned short* __restrict__ A, const unsigned short* __restrict__ wcat,
    const float* __restrict__ bcat,
    unsigned short* __restrict__ qo, unsigned short* __restrict__ ko,
    unsigned short* __restrict__ vto) {
  __shared__ unsigned short sA[12288], sB[12288];   // 3 bufs, 48 KB
  // grid 1280 = (8 m, 5 n, 32 b); chunk 160 = 4 batches/XCD
  const int wid = xcd_swz(blockIdx.x, 1280);
  const int m0 = (wid & 7) * 128, n0 = ((wid >> 3) % 5) * 128, b = wid / 40;
  const int tid = threadIdx.x, wave = tid >> 6, lane = tid & 63;
  f32x4 acc[4][4];
#pragma unroll
  for (int i = 0; i < 4; ++i)
#pragma unroll
    for (int j = 0; j < 4; ++j) acc[i][j] = (f32x4)(0.0f);

  gemm_core32<512>(A + (size_t)b * NN * CC, wcat, m0, n0, tid, sA, sB, acc);

  const int wm = (wave & 1) * 64, wn = (wave >> 1) * 64;
#pragma unroll
  for (int i = 0; i < 4; ++i)
#pragma unroll
    for (int j = 0; j < 4; ++j) {
      int col  = n0 + wn + j * 16 + (lane & 15);
      int rowb = m0 + wm + i * 16 + (lane >> 4) * 4;
      float bias = bcat[col];
      if (col < 64) {
#pragma unroll
        for (int r = 0; r < 4; ++r)
          qo[((size_t)b * NN + rowb + r) * DD + col] = bf16rn(acc[i][j][r] + bias);
      } else if (col < 128) {
#pragma unroll
        for (int r = 0; r < 4; ++r)
          ko[((size_t)b * NN + rowb + r) * DD + col - 64] = bf16rn(acc[i][j][r] + bias);
      } else {
        int c = col - 128;
        us4 pk;
#pragma unroll
        for (int r = 0; r < 4; ++r) pk[r] = bf16rn(acc[i][j][r] + bias);
        *(us4*)(vto + ((size_t)b * CC + c) * NN + rowb) = pk;   // vT: 4 contiguous j
      }
    }
}

// ---------------- fused QK^T + exp (unnormalized P + row-sums) ----------------
// R6-proven numerics (no max-subtraction; absmax unchanged). P-stores issued AFTER
// next tile's loads, waited with COUNTED vmcnt(16) -> the 16 stores drain in the
// background (FIFO retire: <=16 outstanding => the 4 older loads are done).
// Grid 256/group = (8 i, 2 jc, GRP b). LDS 52 KB.
__global__ __launch_bounds__(256) void qkexp_kernel(
    const unsigned short* __restrict__ q, const unsigned short* __restrict__ k,
    float* __restrict__ lpart, unsigned short* __restrict__ P) {
  __shared__ unsigned short sQ[8192];        // 16 KB
  __shared__ unsigned short sK[16384];       // 2x dbuf, 32 KB
  __shared__ float wred[4][128];             // 2 KB

  const int wid = xcd_swz(blockIdx.x, 8 * 2 * GRP);   // chunk 32 = 2 batches/XCD
  const int i0 = (wid & 7) * 128, jc = (wid >> 3) & 1, b = wid >> 4;  // b group-local
  const int jbase = jc * 512;
  const int tid = threadIdx.x, wave = tid >> 6, lane = tid & 63;
  const int wm = (wave & 1) * 64, wn = (wave >> 1) * 64;
  const int fm = lane & 15, kq = lane >> 4;
  const int srow = lane >> 3, sg = (lane & 7) ^ srow;

  const unsigned short* qb = q + (size_t)b * NN * DD;
  const unsigned short* kb = k + (size_t)b * NN * DD;

  auto stageK = [&](int buf, int j0) {
#pragma unroll
    for (int t = 0; t < 4; ++t) {
      const int R = wave * 32 + t * 8;
      gl_lds16(kb + (size_t)(j0 + R + srow) * DD + sg * 8, sK + buf * 8192 + R * 64);
    }
  };

#pragma unroll
  for (int t = 0; t < 4; ++t) {
    const int R = wave * 32 + t * 8;
    gl_lds16(qb + (size_t)(i0 + R + srow) * DD + sg * 8, sQ + R * 64);
  }
  stageK(0, jbase);
  wait_vm0_barrier();

  bf16x8 aq[4][2];   // Q fragments (MFMA B-operand)
#pragma unroll
  for (int i = 0; i < 4; ++i)
#pragma unroll
    for (int kd = 0; kd < 2; ++kd) {
      const int ra = wm + i * 16 + fm;
      aq[i][kd] = *(const bf16x8*)(sQ + ra * 64 + ((kd * 4 + kq) ^ (ra & 7)) * 8);
    }

  float l_l[4] = {0.f, 0.f, 0.f, 0.f};
  us4 pk[4][4];
  int pjt = 0;         // jt of the values currently held in pk

  int cur = 0;
#pragma unroll
  for (int jt = 0; jt < 4; ++jt) {
    if (jt < 3) stageK(cur ^ 1, jbase + (jt + 1) * 128);   // 4 loads (oldest)
    if (jt > 0) {
      // store previous iteration's P tile (16 us4 stores, newer than the loads)
#pragma unroll
      for (int jk = 0; jk < 4; ++jk)
#pragma unroll
        for (int iq = 0; iq < 4; ++iq) {
          const int row = i0 + wm + iq * 16 + fm;
          const int col = jbase + pjt * 128 + wn + jk * 16 + kq * 4;
          *(us4*)(P + ((size_t)b * NN + row) * NN + col) = pk[jk][iq];
        }
    }
    const unsigned short* pK = sK + cur * 8192;
    f32x4 S[4][4];
#pragma unroll
    for (int jk = 0; jk < 4; ++jk)
#pragma unroll
      for (int iq = 0; iq < 4; ++iq) S[jk][iq] = (f32x4)(0.0f);
#pragma unroll
    for (int kd = 0; kd < 2; ++kd) {
      bf16x8 bk[4];
#pragma unroll
      for (int jk = 0; jk < 4; ++jk) {
        const int rb = wn + jk * 16 + fm;
        bk[jk] = *(const bf16x8*)(pK + rb * 64 + ((kd * 4 + kq) ^ (rb & 7)) * 8);
      }
#pragma unroll
      for (int jk = 0; jk < 4; ++jk)
#pragma unroll
        for (int iq = 0; iq < 4; ++iq)
          S[jk][iq] = __builtin_amdgcn_mfma_f32_16x16x32_bf16(bk[jk], aq[iq][kd], S[jk][iq], 0, 0, 0);
    }
#pragma unroll
    for (int jk = 0; jk < 4; ++jk)
#pragma unroll
      for (int iq = 0; iq < 4; ++iq) {
#pragma unroll
        for (int r = 0; r < 4; ++r) {
          float e = __expf(S[jk][iq][r]);
          pk[jk][iq][r] = bf16rn(e);
          l_l[iq] += e;
        }
      }
    pjt = jt;
    if (jt < 3) {
      if (jt == 0) { asm volatile("s_waitcnt vmcnt(0)" ::: "memory"); }   // no stores yet
      else         { asm volatile("s_waitcnt vmcnt(16)" ::: "memory"); }  // loads only
      __builtin_amdgcn_s_barrier();
    }
    cur ^= 1;
  }
  // final P tile (jt=3)
#pragma unroll
  for (int jk = 0; jk < 4; ++jk)
#pragma unroll
    for (int iq = 0; iq < 4; ++iq) {
      const int row = i0 + wm + iq * 16 + fm;
      const int col = jbase + 3 * 128 + wn + jk * 16 + kq * 4;
      *(us4*)(P + ((size_t)b * NN + row) * NN + col) = pk[jk][iq];
    }

  // reduce over the 4 kq lane-groups
#pragma unroll
  for (int iq = 0; iq < 4; ++iq) {
    float l = l_l[iq];
    l += __shfl_xor(l, 16, 64);
    l += __shfl_xor(l, 32, 64);
    l_l[iq] = l;
  }
  if (lane < 16) {
#pragma unroll
    for (int iq = 0; iq < 4; ++iq) wred[wave][wm + iq * 16 + fm] = l_l[iq];
  }
  __syncthreads();
  if (tid < 128) {
    const int a = tid >> 6;
    float l = wred[a][tid] + wred[a + 2][tid];
    lpart[((size_t)b * NN + i0 + tid) * 2 + jc] = l;
  }
}

// ---------------- PV GEMM: Punnorm x vT^T, scale rows by 1/(l0+l1) ----------------
__global__ __launch_bounds__(256) void pv_gemm(
    const unsigned short* __restrict__ P, const unsigned short* __restrict__ vT,
    const float* __restrict__ lpart, unsigned short* __restrict__ attnout) {
  __shared__ unsigned short sA[12288], sB[12288];
  // grid 512/group = (8 m fastest, 4 n, GRP b); chunk 64 = 2 batches/XCD
  const int wid = xcd_swz(blockIdx.x, 8 * 4 * GRP);
  const int m0 = (wid & 7) * 128, n0 = ((wid >> 3) & 3) * 128, b = wid >> 5;
  const int tid = threadIdx.x, wave = tid >> 6, lane = tid & 63;
  f32x4 acc[4][4];
#pragma unroll
  for (int i = 0; i < 4; ++i)
#pragma unroll
    for (int j = 0; j < 4; ++j) acc[i][j] = (f32x4)(0.0f);

  gemm_core32<1024>(P + (size_t)b * NN * NN, vT + (size_t)b * CC * NN, m0, n0, tid, sA, sB, acc);

  const int wm = (wave & 1) * 64, wn = (wave >> 1) * 64;
  float inv[4][4];
#pragma unroll
  for (int i = 0; i < 4; ++i)
#pragma unroll
    for (int r = 0; r < 4; ++r) {
      const int row = m0 + wm + i * 16 + (lane >> 4) * 4 + r;
      float2 lp = *(const float2*)(lpart + ((size_t)b * NN + row) * 2);
      inv[i][r] = 1.0f / (lp.x + lp.y);
    }
#pragma unroll
  for (int i = 0; i < 4; ++i)
#pragma unroll
    for (int j = 0; j < 4; ++j) {
      int col  = n0 + wn + j * 16 + (lane & 15);
      int rowb = m0 + wm + i * 16 + (lane >> 4) * 4;
#pragma unroll
      for (int r = 0; r < 4; ++r)
        attnout[((size_t)b * NN + rowb + r) * CC + col] = bf16rn(acc[i][j][r] * inv[i][r]);
    }
}

// ---------------- output projection ----------------
__global__ __launch_bounds__(256) void outproj_gemm(
    const unsigned short* __restrict__ owb, const unsigned short* __restrict__ attnout,
    const float* __restrict__ ob, float* __restrict__ out) {
  __shared__ unsigned short sA[12288], sB[12288];
  // grid 1024 = (4 m, 8 n, 32 b); chunk 128 = 4 batches/XCD
  const int wid = xcd_swz(blockIdx.x, 1024);
  const int m0 = (wid & 3) * 128, n0 = ((wid >> 2) & 7) * 128, b = wid >> 5;
  const int tid = threadIdx.x, wave = tid >> 6, lane = tid & 63;
  f32x4 acc[4][4];
#pragma unroll
  for (int i = 0; i < 4; ++i)
#pragma unroll
    for (int j = 0; j < 4; ++j) acc[i][j] = (f32x4)(0.0f);

  gemm_core32<512>(owb, attnout + (size_t)b * NN * CC, m0, n0, tid, sA, sB, acc);

  const int wm = (wave & 1) * 64, wn = (wave >> 1) * 64;
#pragma unroll
  for (int i = 0; i < 4; ++i)
#pragma unroll
    for (int j = 0; j < 4; ++j) {
      int col  = n0 + wn + j * 16 + (lane & 15);      // i
      int rowb = m0 + wm + i * 16 + (lane >> 4) * 4;  // co
      f4 b4 = *(const f4*)(ob + rowb);
#pragma unroll
      for (int r = 0; r < 4; ++r)
        out[((size_t)b * CC + rowb + r) * NN + col] = acc[i][j][r] + ((const float*)&b4)[r];
    }
}

extern "C" void kernel_launch(void* const* d_in, const int* in_sizes, int n_in,
                              void* d_out, int out_size, void* d_ws, size_t ws_size,
                              hipStream_t stream) {
  const float* x   = (const float*)d_in[0];
  const float* pos = (const float*)d_in[1];
  const float* qw  = (const float*)d_in[2];
  const float* qb  = (const float*)d_in[3];
  const float* kw  = (const float*)d_in[4];
  const float* kb  = (const float*)d_in[5];
  const float* vw  = (const float*)d_in[6];
  const float* vb  = (const float*)d_in[7];
  const float* ow  = (const float*)d_in[8];
  const float* ob  = (const float*)d_in[9];
  float* out = (float*)d_out;

  // workspace layout (bytes), total ~106 MB (121 MB known-good; 265 MB crashed):
  char* w = (char*)d_ws;
  unsigned short* wcat = (unsigned short*)w; w += (size_t)640 * 512 * 2;        // 0.66 MB
  unsigned short* owb  = (unsigned short*)w; w += (size_t)512 * 512 * 2;        // 0.52 MB
  float*          bcat = (float*)w;          w += 640 * 4;                      // 2.5 KB
  unsigned short* A    = (unsigned short*)w; w += (size_t)BB * NN * CC * 2;     // 32 MB (reused as attnout)
  unsigned short* q    = (unsigned short*)w; w += (size_t)BB * NN * DD * 2;     // 4 MB
  unsigned short* k    = (unsigned short*)w; w += (size_t)BB * NN * DD * 2;     // 4 MB
  unsigned short* vT   = (unsigned short*)w; w += (size_t)BB * CC * NN * 2;     // 32 MB
  float*         lpart = (float*)w;          w += (size_t)BB * NN * 2 * 4;      // 0.25 MB
  unsigned short* PG   = (unsigned short*)w; w += (size_t)GRP * NN * NN * 2;    // 32 MB (per-group)
  unsigned short* attnout = A;  // A is dead after proj_gemm

  hipLaunchKernelGGL(prep_w, dim3(2304), dim3(256), 0, stream,
                     qw, kw, vw, qb, kb, vb, ow, wcat, owb, bcat);
  hipLaunchKernelGGL(prep_x, dim3(16, 8, 32), dim3(256), 0, stream, x, pos, A);
  hipLaunchKernelGGL(proj_gemm, dim3(1280), dim3(256), 0, stream,
                     A, wcat, bcat, q, k, vT);

  for (int g = 0; g < NGRP; ++g) {
    const unsigned short* qg  = q  + (size_t)g * GRP * NN * DD;
    const unsigned short* kg  = k  + (size_t)g * GRP * NN * DD;
    const unsigned short* vTg = vT + (size_t)g * GRP * CC * NN;
    float*                lpg = lpart + (size_t)g * GRP * NN * 2;
    unsigned short* aog = attnout + (size_t)g * GRP * NN * CC;
    hipLaunchKernelGGL(qkexp_kernel, dim3(8 * 2 * GRP), dim3(256), 0, stream,
                       qg, kg, lpg, PG);
    hipLaunchKernelGGL(pv_gemm, dim3(8 * 4 * GRP), dim3(256), 0, stream,
                       PG, vTg, lpg, aog);
  }

  hipLaunchKernelGGL(outproj_gemm, dim3(1024), dim3(256), 0, stream,
                     owb, attnout, ob, out);
}

// Round 9
// 288.187 us; speedup vs baseline: 1.0543x; 1.0543x over previous
//
#include <hip/hip_runtime.h>

// SpatialAttention: B=32, C=512, D=64, N=1024 (H=W=32)
#define BB 32
#define CC 512
#define DD 64
#define NN 1024
#define GRP 16                // batches per P-buffer group
#define NGRP (BB / GRP)       // 2 groups

typedef float4 f4;
typedef __attribute__((ext_vector_type(8))) short bf16x8;     // 8 bf16 = 4 VGPRs (MFMA A/B frag)
typedef __attribute__((ext_vector_type(4))) float f32x4;      // MFMA C/D frag
typedef __attribute__((ext_vector_type(4))) unsigned short us4;
typedef __attribute__((ext_vector_type(8))) unsigned short us8;

__device__ inline unsigned short bf16rn(float f) {
  union { float f; unsigned u; } v; v.f = f;
  unsigned r = v.u + 0x7fff + ((v.u >> 16) & 1);   // round-to-nearest-even
  return (unsigned short)(r >> 16);
}

__device__ inline void gl_lds16(const void* g, void* l) {
  // async global->LDS, 16B/lane; LDS dest = wave-uniform base + lane*16
  __builtin_amdgcn_global_load_lds(
      (const __attribute__((address_space(1))) unsigned int*)g,
      (__attribute__((address_space(3))) unsigned int*)l, 16, 0, 0);
}

__device__ inline void wait_vm0_barrier() {
  asm volatile("s_waitcnt vmcnt(0)" ::: "memory");
  __builtin_amdgcn_s_barrier();
}

// T1: chunked XCD swizzle. nwg%8==0 required.
__device__ inline int xcd_swz(int bid, int nwg) {
  return (bid & 7) * (nwg >> 3) + (bid >> 3);
}

// ---- shared GEMM core (R1/R6-proven): C[128x128] += A[M][K]*Bt[N][K]^T, BK=64 ----
// 2-buffer LDS (64 KB), stage(next) at iter top, vmcnt(0)+barrier at iter end.
// XOR-swizzle: slot s of row r holds global k-group (s ^ (r&7)); 16B groups.
template <int KDIM>
__device__ inline void gemm_core(const unsigned short* __restrict__ A,
                                 const unsigned short* __restrict__ Bt,
                                 int m0, int n0, int tid,
                                 unsigned short* sA, unsigned short* sB,  // 2 x 8192 shorts each
                                 f32x4 acc[4][4]) {
  const int wave = tid >> 6, lane = tid & 63;
  const int wm = (wave & 1) * 64, wn = (wave >> 1) * 64;
  const int fm = lane & 15;           // fragment row (m or n)
  const int kq = lane >> 4;           // fragment k-group (0..3) within 32-k window
  const int srow = lane >> 3;         // staging: row within 8-row slab (0..7)
  const int sg   = (lane & 7) ^ srow; // staging: global k-group (swizzled)

  const unsigned short* ga = A  + (size_t)(m0 + srow) * KDIM + sg * 8;
  const unsigned short* gb = Bt + (size_t)(n0 + srow) * KDIM + sg * 8;

  auto stage = [&](int buf, int k0) {
#pragma unroll
    for (int t = 0; t < 4; ++t) {
      const int R = wave * 32 + t * 8;
      gl_lds16(ga + (size_t)R * KDIM + k0, sA + buf * 8192 + R * 64);
      gl_lds16(gb + (size_t)R * KDIM + k0, sB + buf * 8192 + R * 64);
    }
  };

  stage(0, 0);
  wait_vm0_barrier();

  int cur = 0;
  for (int k0 = 0; k0 < KDIM; k0 += 64) {
    if (k0 + 64 < KDIM) stage(cur ^ 1, k0 + 64);   // prefetch next tile
    const unsigned short* pA = sA + cur * 8192;
    const unsigned short* pB = sB + cur * 8192;
#pragma unroll
    for (int ks = 0; ks < 2; ++ks) {
      bf16x8 af[4], bfr[4];
#pragma unroll
      for (int i = 0; i < 4; ++i) {
        const int ra = wm + i * 16 + fm;
        const int rb = wn + i * 16 + fm;
        af[i]  = *(const bf16x8*)(pA + ra * 64 + ((ks * 4 + kq) ^ (ra & 7)) * 8);
        bfr[i] = *(const bf16x8*)(pB + rb * 64 + ((ks * 4 + kq) ^ (rb & 7)) * 8);
      }
#pragma unroll
      for (int i = 0; i < 4; ++i)
#pragma unroll
        for (int j = 0; j < 4; ++j)
          acc[i][j] = __builtin_amdgcn_mfma_f32_16x16x32_bf16(af[i], bfr[j], acc[i][j], 0, 0, 0);
    }
    wait_vm0_barrier();
    cur ^= 1;
  }
}

// ---------------- prep: weights -> bf16 ----------------
__global__ __launch_bounds__(256) void prep_w(
    const float* __restrict__ qw, const float* __restrict__ kw, const float* __restrict__ vw,
    const float* __restrict__ qb, const float* __restrict__ kb, const float* __restrict__ vb,
    const float* __restrict__ ow,
    unsigned short* __restrict__ wcat, unsigned short* __restrict__ owb,
    float* __restrict__ bcat) {
  int idx = blockIdx.x * 256 + threadIdx.x;
  if (idx < 640 * 512) {
    int row = idx >> 9;
    float v = (row < 64) ? qw[idx] : (row < 128) ? kw[idx - 64 * 512] : vw[idx - 128 * 512];
    wcat[idx] = bf16rn(v);
    if (idx < 640) bcat[idx] = (idx < 64) ? qb[idx] : (idx < 128) ? kb[idx - 64] : vb[idx - 128];
  } else {
    int j = idx - 640 * 512;
    owb[j] = bf16rn(ow[j]);
  }
}

// ---------------- prep: A[b][i][c] = bf16(x[b][c][i] + pos[c][i]) ----------------
__global__ __launch_bounds__(256) void prep_x(const float* __restrict__ x,
                                              const float* __restrict__ pos,
                                              unsigned short* __restrict__ A) {
  __shared__ float t[64][65];
  const int b = blockIdx.z, i0 = blockIdx.x * 64, c0 = blockIdx.y * 64;
  const int tid = threadIdx.x;
  const int ci = tid >> 4, il = (tid & 15) * 4;
  const float* xb = x + (size_t)b * CC * NN;
#pragma unroll
  for (int r = 0; r < 4; ++r) {
    int cl = r * 16 + ci;
    f4 xv = *(const f4*)(xb  + (size_t)(c0 + cl) * NN + i0 + il);
    f4 pv = *(const f4*)(pos + (size_t)(c0 + cl) * NN + i0 + il);
    t[cl][il + 0] = xv.x + pv.x;
    t[cl][il + 1] = xv.y + pv.y;
    t[cl][il + 2] = xv.z + pv.z;
    t[cl][il + 3] = xv.w + pv.w;
  }
  __syncthreads();
  const int iw = tid >> 2, cw = (tid & 3) * 16;
  unsigned short* dst = A + ((size_t)b * NN + i0 + iw) * CC + c0 + cw;
  us8 p0, p1;
#pragma unroll
  for (int j = 0; j < 8; ++j) p0[j] = bf16rn(t[cw + j][iw]);
#pragma unroll
  for (int j = 0; j < 8; ++j) p1[j] = bf16rn(t[cw + 8 + j][iw]);
  *(us8*)dst = p0;
  *(us8*)(dst + 8) = p1;
}

// ---------------- QKV projection GEMM (R6-proven) ----------------
__global__ __launch_bounds__(256) void proj_gemm(
    const unsigned short* __restrict__ A, const unsigned short* __restrict__ wcat,
    const float* __restrict__ bcat,
    unsigned short* __restrict__ qo, unsigned short* __restrict__ ko,
    unsigned short* __restrict__ vto) {
  __shared__ unsigned short sA[16384], sB[16384];   // 2x dbuf, 64 KB
  // grid 1280 = (8 m, 5 n, 32 b); chunk 160 = 4 batches/XCD
  const int wid = xcd_swz(blockIdx.x, 1280);
  const int m0 = (wid & 7) * 128, n0 = ((wid >> 3) % 5) * 128, b = wid / 40;
  const int tid = threadIdx.x, wave = tid >> 6, lane = tid & 63;
  f32x4 acc[4][4];
#pragma unroll
  for (int i = 0; i < 4; ++i)
#pragma unroll
    for (int j = 0; j < 4; ++j) acc[i][j] = (f32x4)(0.0f);

  gemm_core<512>(A + (size_t)b * NN * CC, wcat, m0, n0, tid, sA, sB, acc);

  const int wm = (wave & 1) * 64, wn = (wave >> 1) * 64;
#pragma unroll
  for (int i = 0; i < 4; ++i)
#pragma unroll
    for (int j = 0; j < 4; ++j) {
      int col  = n0 + wn + j * 16 + (lane & 15);
      int rowb = m0 + wm + i * 16 + (lane >> 4) * 4;
      float bias = bcat[col];
      if (col < 64) {
#pragma unroll
        for (int r = 0; r < 4; ++r)
          qo[((size_t)b * NN + rowb + r) * DD + col] = bf16rn(acc[i][j][r] + bias);
      } else if (col < 128) {
#pragma unroll
        for (int r = 0; r < 4; ++r)
          ko[((size_t)b * NN + rowb + r) * DD + col - 64] = bf16rn(acc[i][j][r] + bias);
      } else {
        int c = col - 128;
        us4 pk;
#pragma unroll
        for (int r = 0; r < 4; ++r) pk[r] = bf16rn(acc[i][j][r] + bias);
        *(us4*)(vto + ((size_t)b * CC + c) * NN + rowb) = pk;   // vT: 4 contiguous j
      }
    }
}

// ---------------- fused QK^T + exp (R6-proven): unnormalized P + row-sums ----------------
__global__ __launch_bounds__(256) void qkexp_kernel(
    const unsigned short* __restrict__ q, const unsigned short* __restrict__ k,
    float* __restrict__ lpart, unsigned short* __restrict__ P) {
  __shared__ unsigned short sQ[8192];        // 16 KB
  __shared__ unsigned short sK[16384];       // 2x dbuf, 32 KB
  __shared__ float wred[4][128];             // 2 KB

  const int wid = xcd_swz(blockIdx.x, 8 * 2 * GRP);   // chunk 32 = 2 batches/XCD
  const int i0 = (wid & 7) * 128, jc = (wid >> 3) & 1, b = wid >> 4;  // b group-local
  const int jbase = jc * 512;
  const int tid = threadIdx.x, wave = tid >> 6, lane = tid & 63;
  const int wm = (wave & 1) * 64, wn = (wave >> 1) * 64;
  const int fm = lane & 15, kq = lane >> 4;
  const int srow = lane >> 3, sg = (lane & 7) ^ srow;

  const unsigned short* qb = q + (size_t)b * NN * DD;
  const unsigned short* kb = k + (size_t)b * NN * DD;

  auto stageK = [&](int buf, int j0) {
#pragma unroll
    for (int t = 0; t < 4; ++t) {
      const int R = wave * 32 + t * 8;
      gl_lds16(kb + (size_t)(j0 + R + srow) * DD + sg * 8, sK + buf * 8192 + R * 64);
    }
  };

#pragma unroll
  for (int t = 0; t < 4; ++t) {
    const int R = wave * 32 + t * 8;
    gl_lds16(qb + (size_t)(i0 + R + srow) * DD + sg * 8, sQ + R * 64);
  }
  stageK(0, jbase);
  wait_vm0_barrier();

  bf16x8 aq[4][2];   // Q fragments (MFMA B-operand)
#pragma unroll
  for (int i = 0; i < 4; ++i)
#pragma unroll
    for (int kd = 0; kd < 2; ++kd) {
      const int ra = wm + i * 16 + fm;
      aq[i][kd] = *(const bf16x8*)(sQ + ra * 64 + ((kd * 4 + kq) ^ (ra & 7)) * 8);
    }

  float l_l[4] = {0.f, 0.f, 0.f, 0.f};   // row-sum per iq

  int cur = 0;
#pragma unroll
  for (int jt = 0; jt < 4; ++jt) {
    if (jt < 3) stageK(cur ^ 1, jbase + (jt + 1) * 128);
    const unsigned short* pK = sK + cur * 8192;
    // S^T[jk][iq]: row side = K (kq*4+r -> j), col side = Q (fm -> i)
    f32x4 S[4][4];
#pragma unroll
    for (int jk = 0; jk < 4; ++jk)
#pragma unroll
      for (int iq = 0; iq < 4; ++iq) S[jk][iq] = (f32x4)(0.0f);
#pragma unroll
    for (int kd = 0; kd < 2; ++kd) {
      bf16x8 bk[4];
#pragma unroll
      for (int jk = 0; jk < 4; ++jk) {
        const int rb = wn + jk * 16 + fm;
        bk[jk] = *(const bf16x8*)(pK + rb * 64 + ((kd * 4 + kq) ^ (rb & 7)) * 8);
      }
#pragma unroll
      for (int jk = 0; jk < 4; ++jk)
#pragma unroll
        for (int iq = 0; iq < 4; ++iq)
          S[jk][iq] = __builtin_amdgcn_mfma_f32_16x16x32_bf16(bk[jk], aq[iq][kd], S[jk][iq], 0, 0, 0);
    }
    // exp (fp32) + accumulate row-sum + pack bf16
    us4 pk[4][4];
#pragma unroll
    for (int jk = 0; jk < 4; ++jk)
#pragma unroll
      for (int iq = 0; iq < 4; ++iq) {
#pragma unroll
        for (int r = 0; r < 4; ++r) {
          float e = __expf(S[jk][iq][r]);
          pk[jk][iq][r] = bf16rn(e);
          l_l[iq] += e;
        }
      }
    wait_vm0_barrier();   // drains this iter's stageK + previous iter's P stores
    // P stores after barrier: 4 contiguous cols per us4
#pragma unroll
    for (int jk = 0; jk < 4; ++jk)
#pragma unroll
      for (int iq = 0; iq < 4; ++iq) {
        const int row = i0 + wm + iq * 16 + fm;
        const int col = jbase + jt * 128 + wn + jk * 16 + kq * 4;
        *(us4*)(P + ((size_t)b * NN + row) * NN + col) = pk[jk][iq];
      }
    cur ^= 1;
  }

  // reduce over the 4 kq lane-groups
#pragma unroll
  for (int iq = 0; iq < 4; ++iq) {
    float l = l_l[iq];
    l += __shfl_xor(l, 16, 64);
    l += __shfl_xor(l, 32, 64);
    l_l[iq] = l;
  }
  if (lane < 16) {
#pragma unroll
    for (int iq = 0; iq < 4; ++iq) wred[wave][wm + iq * 16 + fm] = l_l[iq];
  }
  __syncthreads();
  if (tid < 128) {
    const int a = tid >> 6;
    float l = wred[a][tid] + wred[a + 2][tid];
    lpart[((size_t)b * NN + i0 + tid) * 2 + jc] = l;
  }
}

// ---------------- PV GEMM (R6-proven): Punnorm x vT^T, scale rows by 1/(l0+l1) ----------------
__global__ __launch_bounds__(256) void pv_gemm(
    const unsigned short* __restrict__ P, const unsigned short* __restrict__ vT,
    const float* __restrict__ lpart, unsigned short* __restrict__ attnout) {
  __shared__ unsigned short sA[16384], sB[16384];
  // grid 512/group = (8 m fastest, 4 n, GRP b); chunk 64 = 2 batches/XCD
  const int wid = xcd_swz(blockIdx.x, 8 * 4 * GRP);
  const int m0 = (wid & 7) * 128, n0 = ((wid >> 3) & 3) * 128, b = wid >> 5;
  const int tid = threadIdx.x, wave = tid >> 6, lane = tid & 63;
  f32x4 acc[4][4];
#pragma unroll
  for (int i = 0; i < 4; ++i)
#pragma unroll
    for (int j = 0; j < 4; ++j) acc[i][j] = (f32x4)(0.0f);

  gemm_core<1024>(P + (size_t)b * NN * NN, vT + (size_t)b * CC * NN, m0, n0, tid, sA, sB, acc);

  const int wm = (wave & 1) * 64, wn = (wave >> 1) * 64;
  float inv[4][4];
#pragma unroll
  for (int i = 0; i < 4; ++i)
#pragma unroll
    for (int r = 0; r < 4; ++r) {
      const int row = m0 + wm + i * 16 + (lane >> 4) * 4 + r;
      float2 lp = *(const float2*)(lpart + ((size_t)b * NN + row) * 2);
      inv[i][r] = 1.0f / (lp.x + lp.y);
    }
#pragma unroll
  for (int i = 0; i < 4; ++i)
#pragma unroll
    for (int j = 0; j < 4; ++j) {
      int col  = n0 + wn + j * 16 + (lane & 15);
      int rowb = m0 + wm + i * 16 + (lane >> 4) * 4;
#pragma unroll
      for (int r = 0; r < 4; ++r)
        attnout[((size_t)b * NN + rowb + r) * CC + col] = bf16rn(acc[i][j][r] * inv[i][r]);
    }
}

// ---------------- output projection: NEW 256x256 8-wave consumption-ordered core ----------------
// out[b][co][i] = sum_c owb[co][c]*attnout[b][i][c] + ob[co].
// Tile 256(co) x 256(i), K=512 (8 K-tiles of 64). Grid 256 = (2m,4n,32b) = 1 block/CU.
// LDS: 2 buffers x (A 32KB + B 32KB) = 128 KB. 8 waves as 2m x 4n; per-wave out 128x64.
// Staged bytes: 256 blk x 512KB = 131 MB (HALF of the 128^2 version's 262 MB).
// Schedule per K-tile t (4 phases; buf = t&1; staging targets buf^1 = tile t+1):
//   stage order: p0: B slices 0-3 (4 instr); p1: A slices {0,2} (2); p2: A slices {1,3} (2)
//   consumption: phase p reads A slice (wave_m*2 + (p>>1)) and B slice wave_n
//   FIFO ledger (8 outstanding steady): p0 needs prev{B4+A02} = 6 oldest -> vmcnt(2)
//                                       p2 needs prev{A13} = 2 oldest  -> vmcnt(6)
//   (last tile: p2 -> vmcnt(0) since nothing newer was issued). Barriers at p0,p2 only.
//   Loads are thus waited 4 phases (~1 full K-tile) after issue - counted, never drained mid-loop.
__global__ __launch_bounds__(512, 1) void outproj_gemm8(
    const unsigned short* __restrict__ owb, const unsigned short* __restrict__ attnout,
    const float* __restrict__ ob, float* __restrict__ out) {
  __shared__ unsigned short sA[2][16384];   // [buf][256 rows x 64 k]
  __shared__ unsigned short sB[2][16384];

  const int wid = xcd_swz(blockIdx.x, 256);   // chunk 32 = 4 batches/XCD (attnout 4MB in L2)
  const int m0 = (wid & 1) * 256, n0 = ((wid >> 1) & 3) * 256, b = wid >> 3;
  const int tid = threadIdx.x, wave = tid >> 6, lane = tid & 63;
  const int wave_m = wave >> 2, wave_n = wave & 3;   // 2m x 4n
  const int wm = wave_m * 128, wn = wave_n * 64;
  const int fm = lane & 15, kq = lane >> 4;
  const int srow = lane >> 3, sg = (lane & 7) ^ srow;

  const unsigned short* ga = owb + (size_t)(m0 + srow) * 512 + sg * 8;
  const unsigned short* gb = attnout + (size_t)b * NN * CC + (size_t)(n0 + srow) * 512 + sg * 8;

  // one instr stages 8 rows: wave w covers rows (slice*64 + w*8 + srow)
  auto stageB4 = [&](int buf, int k0) {   // all 4 B slices (rows 0..255)
#pragma unroll
    for (int s = 0; s < 4; ++s) {
      const int R = s * 64 + wave * 8;
      gl_lds16(gb + (size_t)R * 512 + k0, &sB[buf][R * 64]);
    }
  };
  auto stageA2 = [&](int buf, int k0, int h) {  // A slices {h, h+2}
#pragma unroll
    for (int t = 0; t < 2; ++t) {
      const int R = (h + t * 2) * 64 + wave * 8;
      gl_lds16(ga + (size_t)R * 512 + k0, &sA[buf][R * 64]);
    }
  };

  f32x4 acc[8][4];
#pragma unroll
  for (int i = 0; i < 8; ++i)
#pragma unroll
    for (int j = 0; j < 4; ++j) acc[i][j] = (f32x4)(0.0f);

  // prologue: tile 0, same issue order as steady state
  stageB4(0, 0); stageA2(0, 0, 0); stageA2(0, 0, 1);

  for (int t = 0; t < 8; ++t) {
    const int cur = t & 1;
    const int k0n = (t + 1) * 64;
    const unsigned short* pA = sA[cur];
    const unsigned short* pB = sB[cur];

#pragma unroll
    for (int p = 0; p < 4; ++p) {
      const int ih = p >> 1, kw = p & 1;
      if (p == 0) {
        asm volatile("s_waitcnt vmcnt(2)" ::: "memory");   // prev B4+A02 retired
        __builtin_amdgcn_s_barrier();
        if (t < 7) stageB4(cur ^ 1, k0n);
      } else if (p == 2) {
        if (t < 7) { asm volatile("s_waitcnt vmcnt(6)" ::: "memory"); }
        else       { asm volatile("s_waitcnt vmcnt(0)" ::: "memory"); }  // drain tail
        __builtin_amdgcn_s_barrier();
        if (t < 7) stageA2(cur ^ 1, k0n, 1);
      } else if (p == 1) {
        if (t < 7) stageA2(cur ^ 1, k0n, 0);
      }
      // ds-read fragments for this phase (A slice wave_m*2+ih; B slice wave_n; k-window kw)
      bf16x8 af[4], bfr[4];
#pragma unroll
      for (int i = 0; i < 4; ++i) {
        const int ra = wm + ih * 64 + i * 16 + fm;
        af[i] = *(const bf16x8*)(pA + ra * 64 + ((kw * 4 + kq) ^ (ra & 7)) * 8);
      }
#pragma unroll
      for (int j = 0; j < 4; ++j) {
        const int rb = wn + j * 16 + fm;
        bfr[j] = *(const bf16x8*)(pB + rb * 64 + ((kw * 4 + kq) ^ (rb & 7)) * 8);
      }
#pragma unroll
      for (int i = 0; i < 4; ++i)
#pragma unroll
        for (int j = 0; j < 4; ++j)
          acc[ih * 4 + i][j] =
              __builtin_amdgcn_mfma_f32_16x16x32_bf16(af[i], bfr[j], acc[ih * 4 + i][j], 0, 0, 0);
    }
  }

  // epilogue: out[b][co][i] = acc + ob[co]
#pragma unroll
  for (int ig = 0; ig < 8; ++ig)
#pragma unroll
    for (int j = 0; j < 4; ++j) {
      int col  = n0 + wn + j * 16 + fm;              // i
      int rowb = m0 + wm + ig * 16 + kq * 4;         // co
      f4 b4 = *(const f4*)(ob + rowb);
#pragma unroll
      for (int r = 0; r < 4; ++r)
        out[((size_t)b * CC + rowb + r) * NN + col] = acc[ig][j][r] + ((const float*)&b4)[r];
    }
}

extern "C" void kernel_launch(void* const* d_in, const int* in_sizes, int n_in,
                              void* d_out, int out_size, void* d_ws, size_t ws_size,
                              hipStream_t stream) {
  const float* x   = (const float*)d_in[0];
  const float* pos = (const float*)d_in[1];
  const float* qw  = (const float*)d_in[2];
  const float* qb  = (const float*)d_in[3];
  const float* kw  = (const float*)d_in[4];
  const float* kb  = (const float*)d_in[5];
  const float* vw  = (const float*)d_in[6];
  const float* vb  = (const float*)d_in[7];
  const float* ow  = (const float*)d_in[8];
  const float* ob  = (const float*)d_in[9];
  float* out = (float*)d_out;

  // workspace layout (bytes), total ~106 MB (121 MB known-good; 265 MB crashed):
  char* w = (char*)d_ws;
  unsigned short* wcat = (unsigned short*)w; w += (size_t)640 * 512 * 2;        // 0.66 MB
  unsigned short* owb  = (unsigned short*)w; w += (size_t)512 * 512 * 2;        // 0.52 MB
  float*          bcat = (float*)w;          w += 640 * 4;                      // 2.5 KB
  unsigned short* A    = (unsigned short*)w; w += (size_t)BB * NN * CC * 2;     // 32 MB (reused as attnout)
  unsigned short* q    = (unsigned short*)w; w += (size_t)BB * NN * DD * 2;     // 4 MB
  unsigned short* k    = (unsigned short*)w; w += (size_t)BB * NN * DD * 2;     // 4 MB
  unsigned short* vT   = (unsigned short*)w; w += (size_t)BB * CC * NN * 2;     // 32 MB
  float*         lpart = (float*)w;          w += (size_t)BB * NN * 2 * 4;      // 0.25 MB
  unsigned short* PG   = (unsigned short*)w; w += (size_t)GRP * NN * NN * 2;    // 32 MB (per-group)
  unsigned short* attnout = A;  // A is dead after proj_gemm

  hipLaunchKernelGGL(prep_w, dim3(2304), dim3(256), 0, stream,
                     qw, kw, vw, qb, kb, vb, ow, wcat, owb, bcat);
  hipLaunchKernelGGL(prep_x, dim3(16, 8, 32), dim3(256), 0, stream, x, pos, A);
  hipLaunchKernelGGL(proj_gemm, dim3(1280), dim3(256), 0, stream,
                     A, wcat, bcat, q, k, vT);

  for (int g = 0; g < NGRP; ++g) {
    const unsigned short* qg  = q  + (size_t)g * GRP * NN * DD;
    const unsigned short* kg  = k  + (size_t)g * GRP * NN * DD;
    const unsigned short* vTg = vT + (size_t)g * GRP * CC * NN;
    float*                lpg = lpart + (size_t)g * GRP * NN * 2;
    unsigned short* aog = attnout + (size_t)g * GRP * NN * CC;
    hipLaunchKernelGGL(qkexp_kernel, dim3(8 * 2 * GRP), dim3(256), 0, stream,
                       qg, kg, lpg, PG);
    hipLaunchKernelGGL(pv_gemm, dim3(8 * 4 * GRP), dim3(256), 0, stream,
                       PG, vTg, lpg, aog);
  }

  hipLaunchKernelGGL(outproj_gemm8, dim3(256), dim3(512), 0, stream,
                     owb, attnout, ob, out);
}